// Round 11
// baseline (528.811 us; speedup 1.0000x reference)
//
#include <hip/hip_runtime.h>
#include <hip/hip_fp16.h>

// GIN_MLP: 2x GIN conv (N=100000, E=1.6M, H=128) + per-batch context MLP (B=4096).
// Device-built dst-CSR (rank-based atomic-free scatter, 8-aligned padded rows)
// -> fused aggregate+GEMM -> tiled final MLP. fp16 node state throughout.
// R22 = R21 with the macro-parameter bug fixed (param `w` collided with the
// `.w` member token under preprocessor substitution -> renamed `wt`).
// R21 design: conv obeys T=84+496/M us (M = per-wave gathers in flight;
// verified M=2,3,4,8). Prior M=16 attempts died on register bytes per
// in-flight edge. New geometry: fp16 row (256B) = 64 lanes x 4B -> ONE dword
// gather per edge (1 VGPR payload/edge). M=16 = 16 payload + 16 weight VGPR.
// Descriptors off the register file: block's padded edge list (<=1024 typ.)
// cooperatively staged once into 8KB LDS, consumed via uniform ds_read_b128
// (lgkm only); wave-uniform global fallback past 1024. A/B sub-batch rotation
// keeps 8-16 gathers in flight; compiler's staged vmcnt does the waits.
// acc per-lane (2l,2l+1) -> natural xm layout -> de-permute pass deleted.
// Tripwire: WRITE>100MB = spill -> revert to R20.

#define CONV_NPB 32
#define FIN_EPB 8

struct __align__(8)  h4 { __half2 a, b; };
struct __align__(16) h8 { __half2 a, b, c, d; };

__device__ __forceinline__ float4 h4f(h4 u) {
  return make_float4(__low2float(u.a), __high2float(u.a),
                     __low2float(u.b), __high2float(u.b));
}
__device__ __forceinline__ h4 f4h(float4 v) {
  h4 u; u.a = __floats2half2_rn(v.x, v.y); u.b = __floats2half2_rn(v.z, v.w);
  return u;
}

// merged init+hist (R18, proven): weight transposes + fp16 cast of ndata
// + per-dst degree & per-edge rank. cnt zeroed by hipMemsetAsync before.
__global__ void inithist_kernel(const float* __restrict__ W1, const float* __restrict__ W2,
                                const float* __restrict__ Wc1, const float* __restrict__ Wc2,
                                const float* __restrict__ ndata, __half* __restrict__ xh0,
                                float* __restrict__ Wt1, float* __restrict__ Wt2,
                                float* __restrict__ Wc1t, float* __restrict__ Wc2t,
                                const int* __restrict__ dst, int* __restrict__ cnt,
                                int* __restrict__ rank, int n, int E) {
  int i = blockIdx.x * blockDim.x + threadIdx.x;
  int e = i * 4;
  if (e + 3 < E) {
    const int4 d = *(const int4*)&dst[e];
    int4 r;
    r.x = atomicAdd(&cnt[d.x], 1);
    r.y = atomicAdd(&cnt[d.y], 1);
    r.z = atomicAdd(&cnt[d.z], 1);
    r.w = atomicAdd(&cnt[d.w], 1);
    *(int4*)&rank[e] = r;
  } else {
    for (; e < E; ++e) rank[e] = atomicAdd(&cnt[dst[e]], 1);
  }
  const int cbase = i * 8;
  if (cbase < n * 128) {
    const float4 v0 = *(const float4*)&ndata[cbase];
    const float4 v1 = *(const float4*)&ndata[cbase + 4];
    h8 u;
    u.a = __floats2half2_rn(v0.x, v0.y);
    u.b = __floats2half2_rn(v0.z, v0.w);
    u.c = __floats2half2_rn(v1.x, v1.y);
    u.d = __floats2half2_rn(v1.z, v1.w);
    *(h8*)&xh0[cbase] = u;
  }
  if (i < 16384) {
    int f = i >> 7, k = i & 127;
    Wt1[k * 128 + f] = W1[i];
  } else if (i < 32768) {
    int j = i - 16384; int f = j >> 7, k = j & 127;
    Wt2[k * 128 + f] = W2[j];
  } else if (i < 81920) {
    int j = i - 32768; int f = j / 384, k = j % 384;
    Wc1t[k * 128 + f] = Wc1[j];
  } else if (i < 90112) {
    int j = i - 81920; int f = j >> 7, k = j & 127;
    Wc2t[k * 64 + f] = Wc2[j];
  }
}

// per-2048-chunk exclusive scan of PADDED counts (ceil(cnt/8)*8); bsum[b] = chunk total
__global__ void scan1_kernel(const int* __restrict__ cnt, int* __restrict__ prow,
                             int* __restrict__ bsum, int n) {
  __shared__ int smem[256];
  const int t = threadIdx.x;
  const int base = blockIdx.x * 2048 + t * 8;
  int v[8];
  int s = 0;
#pragma unroll
  for (int j = 0; j < 8; ++j) {
    int idx = base + j;
    v[j] = (idx < n) ? ((cnt[idx] + 7) & ~7) : 0;
    s += v[j];
  }
  smem[t] = s;
  __syncthreads();
  for (int off = 1; off < 256; off <<= 1) {
    int add = (t >= off) ? smem[t - off] : 0;
    __syncthreads();
    smem[t] += add;
    __syncthreads();
  }
  int run = smem[t] - s;
  if (t == 255) bsum[blockIdx.x] = smem[255];
#pragma unroll
  for (int j = 0; j < 8; ++j) {
    int idx = base + j;
    if (idx < n) prow[idx] = run;
    run += v[j];
  }
}

// 64-lane shuffle scan (nchunk=49 fits); appends grand total at bsum[nb]
__global__ void scan2_kernel(int* __restrict__ bsum, int nb) {
  const int t = threadIdx.x;
  if (nb <= 64) {
    const int orig = (t < nb) ? bsum[t] : 0;
    int v = orig;
#pragma unroll
    for (int off = 1; off < 64; off <<= 1) {
      int u = __shfl_up(v, off);
      if (t >= off) v += u;
    }
    if (t == nb - 1) bsum[nb] = v;
    if (t < nb) bsum[t] = v - orig;
  } else if (t == 0) {
    int run = 0;
    for (int i = 0; i < nb; ++i) { int v = bsum[i]; bsum[i] = run; run += v; }
    bsum[nb] = run;
  }
}

// atomic-free scatter into padded CSR, 4 edges/thread; threads i<n also zero
// their node's pad slots (real + pad slots exactly partition the padded CSR)
__global__ void scatter_kernel(const int* __restrict__ src, const int* __restrict__ dst,
                               const float* __restrict__ w, const int* __restrict__ prow,
                               const int* __restrict__ bsum, const int* __restrict__ rank,
                               const int* __restrict__ cnt,
                               int2* __restrict__ epack, int E, int n) {
  const int i = blockIdx.x * blockDim.x + threadIdx.x;
  int e = i * 4;
  if (e + 3 < E) {
    const int4 d = *(const int4*)&dst[e];
    const int4 s = *(const int4*)&src[e];
    const float4 wv = *(const float4*)&w[e];
    const int4 r = *(const int4*)&rank[e];
    epack[prow[d.x] + bsum[d.x >> 11] + r.x] = make_int2(s.x, __float_as_int(wv.x));
    epack[prow[d.y] + bsum[d.y >> 11] + r.y] = make_int2(s.y, __float_as_int(wv.y));
    epack[prow[d.z] + bsum[d.z >> 11] + r.z] = make_int2(s.z, __float_as_int(wv.z));
    epack[prow[d.w] + bsum[d.w >> 11] + r.w] = make_int2(s.w, __float_as_int(wv.w));
  } else {
    for (; e < E; ++e) {
      const int d = dst[e];
      epack[prow[d] + bsum[d >> 11] + rank[e]] = make_int2(src[e], __float_as_int(w[e]));
    }
  }
  if (i < n) {
    const int c = cnt[i];
    const int start = prow[i] + bsum[i >> 11] + c;
    const int pc = ((c + 7) & ~7) - c;
    for (int j = 0; j < pc; ++j) epack[start + j] = make_int2(0, 0);
  }
}

// R22 conv (R21 design). Stage 1: one-row-per-inst dword gathers (64 lanes x
// 4B = one fp16 row; lane holds features 2l,2l+1). Per wave: contiguous range
// of 8-edge sub-batches (8-aligned padding => each sub-batch in ONE dst row).
// A/B rotation: issue 8 dword gathers for sb+1 while consuming sb (M ~ 8-16).
// Descriptors: block's first 1024 padded edges staged cooperatively in LDS,
// read via uniform ds_read_b128 (lgkm-only); global int4 fallback past 1024
// (wave-uniform branch). acc = float2/lane, natural layout -> no de-permute.
// Stage 2: in-place (1+eps)x + agg/deg. Stage 3: GEMM f32. fp16 epilogue.
__launch_bounds__(256, 6)
__global__ void conv_kernel(const float* __restrict__ xinf, const __half* __restrict__ xinh,
                            __half* __restrict__ xouth,
                            const int* __restrict__ prow, const int* __restrict__ bsum,
                            const int* __restrict__ cnt,
                            const int2* __restrict__ epack,
                            const float* __restrict__ Wt,
                            const float* __restrict__ bias, const float* __restrict__ eps,
                            int epsidx, int dorelu, int zerorow0, int selff32,
                            int n, int nchunk) {
  __shared__ float xm[CONV_NPB * 128];
  __shared__ int4 dscb[512];               // 8KB: first 1024 edges' (src,w)
  __shared__ int rp_s[CONV_NPB + 1];
  const int t = threadIdx.x;
  const int nb = blockIdx.x * CONV_NPB;
  const float epsv = 1.0f + eps[epsidx];

#pragma unroll
  for (int i = 0; i < 4; ++i)
    *(float4*)&xm[(t + i * 256) * 4] = make_float4(0.f, 0.f, 0.f, 0.f);
  if (t <= CONV_NPB) {
    const int node = nb + t;
    rp_s[t] = (node >= n) ? bsum[nchunk] : (prow[node] + bsum[node >> 11]);
  }
  __syncthreads();

  const int e0 = rp_s[0], eT = rp_s[CONV_NPB];
  // cooperative descriptor staging (coalesced int2 loads)
  {
    const int tot = eT - e0;
    const int staged = (tot < 1024) ? tot : 1024;
    const int2* ep2 = (const int2*)epack;
    int2* d2 = (int2*)dscb;
    for (int o = t; o < staged; o += 256) d2[o] = ep2[e0 + o];
  }
  __syncthreads();

  // ---- stage 1: A/B-rotated one-row-per-inst gather ----
  {
    const int wid = t >> 6;
    const int lane = t & 63;
    const int nsb = (eT - e0) >> 3;           // 8-edge sub-batches in block
    const int sbLDS = ((eT - e0) < 1024 ? (eT - e0) : 1024) >> 3;
    const int csb = (nsb + 3) >> 2;
    const int sb0 = wid * csb;
    const int sbend = min(sb0 + csb, nsb);
    if (sb0 < sbend) {
      const int4* ep4 = (const int4*)epack;
      const int h0 = e0 >> 1;                 // e0 is 8-aligned => even
      const unsigned int* xu = (const unsigned int*)xinh;
      int r = 0;
      { const int j0 = e0 + sb0 * 8; while (rp_s[r + 1] <= j0) ++r; }
      float ax = 0.f, ay = 0.f;

#define LOADD(sb_, q0, q1, q2, q3) do {                                   \
      if ((sb_) < sbLDS) {                                                \
        q0 = dscb[(sb_) * 4 + 0]; q1 = dscb[(sb_) * 4 + 1];               \
        q2 = dscb[(sb_) * 4 + 2]; q3 = dscb[(sb_) * 4 + 3];               \
      } else {                                                            \
        q0 = ep4[h0 + (sb_) * 4 + 0]; q1 = ep4[h0 + (sb_) * 4 + 1];       \
        q2 = ep4[h0 + (sb_) * 4 + 2]; q3 = ep4[h0 + (sb_) * 4 + 3];       \
      } } while (0)

#define GATHER8(q0, q1, q2, q3, uu, wt) do {                              \
      wt[0] = __int_as_float(q0.y); wt[1] = __int_as_float(q0.w);         \
      wt[2] = __int_as_float(q1.y); wt[3] = __int_as_float(q1.w);         \
      wt[4] = __int_as_float(q2.y); wt[5] = __int_as_float(q2.w);         \
      wt[6] = __int_as_float(q3.y); wt[7] = __int_as_float(q3.w);         \
      uu[0] = xu[(size_t)q0.x * 64 + lane];                               \
      uu[1] = xu[(size_t)q0.z * 64 + lane];                               \
      uu[2] = xu[(size_t)q1.x * 64 + lane];                               \
      uu[3] = xu[(size_t)q1.z * 64 + lane];                               \
      uu[4] = xu[(size_t)q2.x * 64 + lane];                               \
      uu[5] = xu[(size_t)q2.z * 64 + lane];                               \
      uu[6] = xu[(size_t)q3.x * 64 + lane];                               \
      uu[7] = xu[(size_t)q3.z * 64 + lane];                               \
    } while (0)

#define CONSUME8(uu, wt) do {                                             \
      _Pragma("unroll")                                                   \
      for (int k = 0; k < 8; ++k) {                                       \
        const float2 f = __half22float2(*(const __half2*)&uu[k]);         \
        ax += wt[k] * f.x; ay += wt[k] * f.y;                             \
      } } while (0)

#define ROWWALK(sb_) do {                                                 \
      const int j = e0 + (sb_) * 8;                                       \
      if (rp_s[r + 1] <= j) {                                             \
        atomicAdd(&xm[r * 128 + lane * 2],     ax);                       \
        atomicAdd(&xm[r * 128 + lane * 2 + 1], ay);                       \
        ax = 0.f; ay = 0.f;                                               \
        do { ++r; } while (rp_s[r + 1] <= j);                             \
      } } while (0)

      int4 qa0, qa1, qa2, qa3, qb0, qb1, qb2, qb3;
      unsigned int uA[8], uB[8];
      float wA[8], wB[8];
      LOADD(sb0, qa0, qa1, qa2, qa3);
      GATHER8(qa0, qa1, qa2, qa3, uA, wA);
      int sb = sb0;
      while (true) {
        // current = A(sb); issue B(sb+1)
        if (sb + 1 < sbend) {
          LOADD(sb + 1, qb0, qb1, qb2, qb3);
          GATHER8(qb0, qb1, qb2, qb3, uB, wB);
        }
        ROWWALK(sb);
        CONSUME8(uA, wA);
        ++sb; if (sb >= sbend) break;
        // current = B(sb); issue A(sb+1)
        if (sb + 1 < sbend) {
          LOADD(sb + 1, qa0, qa1, qa2, qa3);
          GATHER8(qa0, qa1, qa2, qa3, uA, wA);
        }
        ROWWALK(sb);
        CONSUME8(uB, wB);
        ++sb; if (sb >= sbend) break;
      }
      atomicAdd(&xm[r * 128 + lane * 2],     ax);
      atomicAdd(&xm[r * 128 + lane * 2 + 1], ay);
#undef LOADD
#undef GATHER8
#undef CONSUME8
#undef ROWWALK
    }
  }
  __syncthreads();

  // ---- stage 2: in-place finalize (1+eps)*x + agg/deg (natural layout) ----
  {
#pragma unroll
    for (int q = 0; q < 4; ++q) {
      const int task = t + q * 256;
      const int r = task >> 5;
      const int fg = task & 31;
      const int f0 = fg * 4;
      const int node = nb + r;
      float4 v = make_float4(0.f, 0.f, 0.f, 0.f);
      if (node < n) {
        const int d = cnt[node];
        const float rdeg = 1.0f / (float)(d > 1 ? d : 1);
        float4 xv;
        if (selff32) xv = *(const float4*)&xinf[(size_t)node * 128 + f0];
        else         xv = h4f(*(const h4*)&xinh[(size_t)node * 128 + f0]);
        const float4 m = *(const float4*)&xm[r * 128 + f0];
        v.x = epsv * xv.x + m.x * rdeg;
        v.y = epsv * xv.y + m.y * rdeg;
        v.z = epsv * xv.z + m.z * rdeg;
        v.w = epsv * xv.w + m.w * rdeg;
      }
      *(float4*)&xm[r * 128 + f0] = v;   // each (r,f0) owned by one thread
    }
  }
  __syncthreads();

  // ---- stage 3: GEMM, thread tile = 4 rows x 4 features ----
  {
    const int fg = t & 31;
    const int rg = t >> 5;
    const int f0 = fg * 4;
    const int r0 = rg * 4;
    float4 acc[4];
#pragma unroll
    for (int r = 0; r < 4; ++r) acc[r] = make_float4(0.f, 0.f, 0.f, 0.f);
    for (int k = 0; k < 128; k += 4) {
      const float4 w0 = *(const float4*)&Wt[(k + 0) * 128 + f0];
      const float4 w1 = *(const float4*)&Wt[(k + 1) * 128 + f0];
      const float4 w2 = *(const float4*)&Wt[(k + 2) * 128 + f0];
      const float4 w3 = *(const float4*)&Wt[(k + 3) * 128 + f0];
#pragma unroll
      for (int r = 0; r < 4; ++r) {
        const float4 xv = *(const float4*)&xm[(r0 + r) * 128 + k];
        acc[r].x += xv.x * w0.x + xv.y * w1.x + xv.z * w2.x + xv.w * w3.x;
        acc[r].y += xv.x * w0.y + xv.y * w1.y + xv.z * w2.y + xv.w * w3.y;
        acc[r].z += xv.x * w0.z + xv.y * w1.z + xv.z * w2.z + xv.w * w3.z;
        acc[r].w += xv.x * w0.w + xv.y * w1.w + xv.z * w2.w + xv.w * w3.w;
      }
    }
    const float4 bv = *(const float4*)&bias[f0];
#pragma unroll
    for (int r = 0; r < 4; ++r) {
      const int node = nb + r0 + r;
      if (node < n) {
        float4 v;
        v.x = acc[r].x + bv.x;
        v.y = acc[r].y + bv.y;
        v.z = acc[r].z + bv.z;
        v.w = acc[r].w + bv.w;
        if (dorelu) {
          v.x = fmaxf(v.x, 0.f); v.y = fmaxf(v.y, 0.f);
          v.z = fmaxf(v.z, 0.f); v.w = fmaxf(v.w, 0.f);
        }
        if (zerorow0 && node == 0) { v.x = 0.f; v.y = 0.f; v.z = 0.f; v.w = 0.f; }
        *(h4*)&xouth[(size_t)node * 128 + f0] = f4h(v);
      }
    }
  }
}

// Final MLP: 8 elems per 256-thread block (512 blocks); x2 gathers in fp16.
__launch_bounds__(256, 4)
__global__ void final_kernel(const __half* __restrict__ x2h, const int* __restrict__ indices,
                             const float* __restrict__ Wc1t, const float* __restrict__ bc1,
                             const float* __restrict__ Wc2t, const float* __restrict__ bc2,
                             const float* __restrict__ Wc3, const float* __restrict__ bc3,
                             float* __restrict__ out) {
  __shared__ float ysm[FIN_EPB * 384];
  __shared__ float h1s[FIN_EPB * 128];
  __shared__ float h2s[FIN_EPB * 64];
  __shared__ int ind_s[FIN_EPB * 23];
  __shared__ float ccs[FIN_EPB];
  const int t = threadIdx.x;
  const int b0 = blockIdx.x * FIN_EPB;

  if (t < FIN_EPB * 23) ind_s[t] = indices[(size_t)b0 * 23 + t];
  __syncthreads();
  if (t < FIN_EPB) {
    int cc = 0;
#pragma unroll
    for (int j = 0; j < 20; ++j) cc += (ind_s[t * 23 + 3 + j] > 0) ? 1 : 0;
    ccs[t] = 1.0f / (float)(cc > 0 ? cc : 1);
  }
  __syncthreads();

  // ---- phase A ----
  {
#pragma unroll
    for (int q = 0; q < 2; ++q) {
      const int s = t + q * 256;
      const int e = s >> 6;
      const int hf = (s >> 5) & 1;
      const int fg = s & 31;
      const int idx = ind_s[e * 23 + hf];
      const h4 u = *(const h4*)&x2h[(size_t)idx * 128 + fg * 4];
      *(float4*)&ysm[e * 384 + hf * 128 + fg * 4] = h4f(u);
    }
    const int e = t >> 5;
    const int fg = t & 31;
    float4 acc = make_float4(0.f, 0.f, 0.f, 0.f);
#pragma unroll
    for (int j = 0; j < 20; ++j) {
      const int cj = ind_s[e * 23 + 3 + j];
      const h4 u = *(const h4*)&x2h[(size_t)cj * 128 + fg * 4];
      const float4 a = h4f(u);
      acc.x += a.x; acc.y += a.y; acc.z += a.z; acc.w += a.w;
    }
    const float sc = ccs[e];
    acc.x *= sc; acc.y *= sc; acc.z *= sc; acc.w *= sc;
    *(float4*)&ysm[e * 384 + 256 + fg * 4] = acc;
  }
  __syncthreads();

  // ---- phase B: layer 1 (384 -> 128), 4 elems per thread ----
  {
    const int f1 = t & 127;
    const int eh = t >> 7;
    float acc[4];
    const float b = bc1[f1];
#pragma unroll
    for (int i = 0; i < 4; ++i) acc[i] = b;
    for (int k = 0; k < 384; k += 4) {
      const float wv0 = Wc1t[(k + 0) * 128 + f1];
      const float wv1 = Wc1t[(k + 1) * 128 + f1];
      const float wv2 = Wc1t[(k + 2) * 128 + f1];
      const float wv3 = Wc1t[(k + 3) * 128 + f1];
#pragma unroll
      for (int i = 0; i < 4; ++i) {
        const float4 yv = *(const float4*)&ysm[(eh * 4 + i) * 384 + k];
        acc[i] += yv.x * wv0 + yv.y * wv1 + yv.z * wv2 + yv.w * wv3;
      }
    }
#pragma unroll
    for (int i = 0; i < 4; ++i)
      h1s[(eh * 4 + i) * 128 + f1] = fmaxf(acc[i], 0.f);
  }
  __syncthreads();

  // ---- phase C: layer 2 (128 -> 64), 2 elems per thread ----
  {
    const int f2 = t & 63;
    const int eg = t >> 6;
    float acc[2];
    const float b = bc2[f2];
#pragma unroll
    for (int i = 0; i < 2; ++i) acc[i] = b;
    for (int k = 0; k < 128; k += 4) {
      const float wv0 = Wc2t[(k + 0) * 64 + f2];
      const float wv1 = Wc2t[(k + 1) * 64 + f2];
      const float wv2 = Wc2t[(k + 2) * 64 + f2];
      const float wv3 = Wc2t[(k + 3) * 64 + f2];
#pragma unroll
      for (int i = 0; i < 2; ++i) {
        const float4 hv = *(const float4*)&h1s[(eg * 2 + i) * 128 + k];
        acc[i] += hv.x * wv0 + hv.y * wv1 + hv.z * wv2 + hv.w * wv3;
      }
    }
#pragma unroll
    for (int i = 0; i < 2; ++i)
      h2s[(eg * 2 + i) * 64 + f2] = fmaxf(acc[i], 0.f);
  }
  __syncthreads();

  // ---- phase D: layer 3 (64 -> 1), 32 lanes per element ----
  {
    const int e = t >> 5;
    const int l = t & 31;
    float p = h2s[e * 64 + l] * Wc3[l] + h2s[e * 64 + l + 32] * Wc3[l + 32];
#pragma unroll
    for (int o = 16; o > 0; o >>= 1) p += __shfl_down(p, o, 32);
    if (l == 0) out[b0 + e] = p + bc3[0];
  }
}

extern "C" void kernel_launch(void* const* d_in, const int* in_sizes, int n_in,
                              void* d_out, int out_size, void* d_ws, size_t ws_size,
                              hipStream_t stream) {
  const int* indices = (const int*)d_in[0];
  const int* src = (const int*)d_in[1];
  const int* dst = (const int*)d_in[2];
  const float* w = (const float*)d_in[3];
  const float* ndata = (const float*)d_in[4];
  const float* W1 = (const float*)d_in[5];
  const float* b1 = (const float*)d_in[6];
  const float* W2 = (const float*)d_in[7];
  const float* b2 = (const float*)d_in[8];
  const float* eps = (const float*)d_in[9];
  const float* Wc1 = (const float*)d_in[10];
  const float* bc1 = (const float*)d_in[11];
  const float* Wc2 = (const float*)d_in[12];
  const float* bc2 = (const float*)d_in[13];
  const float* Wc3 = (const float*)d_in[14];
  const float* bc3 = (const float*)d_in[15];
  float* out = (float*)d_out;

  const int E = in_sizes[1];
  const int N = in_sizes[4] / 128;
  const int B = in_sizes[0] / 23;

  char* ws = (char*)d_ws;
  size_t off = 0;
  auto alloc = [&](size_t bytes) -> char* {
    char* p = ws + off;
    off = (off + bytes + 255) & ~(size_t)255;
    return p;
  };
  const size_t Epad = (size_t)E + 8 * (size_t)N;   // worst-case padded edge count
  int* cnt = (int*)alloc((size_t)N * 4);
  int* prow = (int*)alloc((size_t)(N + 1) * 4);
  int* rank = (int*)alloc((size_t)E * 4);
  int* bsum = (int*)alloc(256 * 4);
  int2* epack = (int2*)alloc(Epad * 8);
  __half* xh0 = (__half*)alloc((size_t)N * 128 * 2);       // fp16 ndata; reused as x2h
  __half* x1h = (__half*)alloc((size_t)N * 128 * 2);       // fp16 x1
  float* Wt1 = (float*)alloc(16384 * 4);
  float* Wt2 = (float*)alloc(16384 * 4);
  float* Wc1t = (float*)alloc(49152 * 4);
  float* Wc2t = (float*)alloc(8192 * 4);
  __half* x2h = xh0;   // xh0 dead after conv1; conv2 writes x2 (fp16) here

  // cnt = 0 (stream-ordered; completes before inithist's atomics)
  (void)hipMemsetAsync(cnt, 0, (size_t)N * 4, stream);

  const int ncast = (N * 128 + 7) / 8;                     // 1.6M cast threads
  const int Eq = (E + 3) / 4;
  int ninit = (N > 90112) ? N : 90112;
  if (ncast > ninit) ninit = ncast;
  if (Eq > ninit) ninit = Eq;
  inithist_kernel<<<(ninit + 255) / 256, 256, 0, stream>>>(
      W1, W2, Wc1, Wc2, ndata, xh0, Wt1, Wt2, Wc1t, Wc2t, dst, cnt, rank, N, E);

  const int nchunk = (N + 2047) / 2048;
  scan1_kernel<<<nchunk, 256, 0, stream>>>(cnt, prow, bsum, N);
  scan2_kernel<<<1, 64, 0, stream>>>(bsum, nchunk);
  const int nsc = (Eq > N) ? Eq : N;
  scatter_kernel<<<(nsc + 255) / 256, 256, 0, stream>>>(src, dst, w, prow, bsum, rank, cnt, epack, E, N);

  const int nconv = (N + CONV_NPB - 1) / CONV_NPB;
  // conv1: gathers fp16(ndata); self term f32 ndata; writes x1h (fp16 only)
  conv_kernel<<<nconv, 256, 0, stream>>>(ndata, xh0, x1h, prow, bsum, cnt, epack,
                                         Wt1, b1, eps, 0, 1, 0, 1, N, nchunk);
  // conv2: gathers x1h; self term fp16 x1h; writes x2h (into xh0 buffer)
  conv_kernel<<<nconv, 256, 0, stream>>>(nullptr, x1h, x2h, prow, bsum, cnt, epack,
                                         Wt2, b2, eps, 1, 0, 1, 0, N, nchunk);

  final_kernel<<<B / FIN_EPB, 256, 0, stream>>>(x2h, indices, Wc1t, bc1, Wc2t, bc2, Wc3, bc3, out);
}

// Round 12
// 509.926 us; speedup vs baseline: 1.0370x; 1.0370x over previous
//
#include <hip/hip_runtime.h>
#include <hip/hip_fp16.h>

// GIN_MLP: 2x GIN conv (N=100000, E=1.6M, H=128) + per-batch context MLP (B=4096).
// Device-built dst-CSR (rank-based atomic-free scatter, 8-aligned padded rows)
// -> fused aggregate+GEMM -> tiled final MLP. fp16 node state throughout.
// R23 = R20 verbatim (proven best: 511.8us; conv 144us each). Conv gather is
// at the CU-level in-flight-gather saturation wall: T=84+496/M us per-wave
// with occupancy x M capped (7-experiment sweep: R12 M=2/320, R16 M=4/208,
// R14 M=8/146, R22 M~7/157 at lower occupancy; R15/R17 spilled, R19's
// direct-to-LDS serialized on waitcnt). M=8 laneset-h4 fp16 gather +
// descriptor prefetch at 8 blk/CU is the demonstrated practical HIP floor.
// Tail (~224us: inithist/scan/scatter/final) is diffuse latency/launch cost.

#define CONV_NPB 32
#define FIN_EPB 8

struct __align__(8)  h4 { __half2 a, b; };
struct __align__(16) h8 { __half2 a, b, c, d; };

__device__ __forceinline__ float4 h4f(h4 u) {
  return make_float4(__low2float(u.a), __high2float(u.a),
                     __low2float(u.b), __high2float(u.b));
}
__device__ __forceinline__ h4 f4h(float4 v) {
  h4 u; u.a = __floats2half2_rn(v.x, v.y); u.b = __floats2half2_rn(v.z, v.w);
  return u;
}

// merged init+hist (R18, proven): weight transposes + fp16 cast of ndata
// + per-dst degree & per-edge rank. cnt zeroed by hipMemsetAsync before.
__global__ void inithist_kernel(const float* __restrict__ W1, const float* __restrict__ W2,
                                const float* __restrict__ Wc1, const float* __restrict__ Wc2,
                                const float* __restrict__ ndata, __half* __restrict__ xh0,
                                float* __restrict__ Wt1, float* __restrict__ Wt2,
                                float* __restrict__ Wc1t, float* __restrict__ Wc2t,
                                const int* __restrict__ dst, int* __restrict__ cnt,
                                int* __restrict__ rank, int n, int E) {
  int i = blockIdx.x * blockDim.x + threadIdx.x;
  int e = i * 4;
  if (e + 3 < E) {
    const int4 d = *(const int4*)&dst[e];
    int4 r;
    r.x = atomicAdd(&cnt[d.x], 1);
    r.y = atomicAdd(&cnt[d.y], 1);
    r.z = atomicAdd(&cnt[d.z], 1);
    r.w = atomicAdd(&cnt[d.w], 1);
    *(int4*)&rank[e] = r;
  } else {
    for (; e < E; ++e) rank[e] = atomicAdd(&cnt[dst[e]], 1);
  }
  const int cbase = i * 8;
  if (cbase < n * 128) {
    const float4 v0 = *(const float4*)&ndata[cbase];
    const float4 v1 = *(const float4*)&ndata[cbase + 4];
    h8 u;
    u.a = __floats2half2_rn(v0.x, v0.y);
    u.b = __floats2half2_rn(v0.z, v0.w);
    u.c = __floats2half2_rn(v1.x, v1.y);
    u.d = __floats2half2_rn(v1.z, v1.w);
    *(h8*)&xh0[cbase] = u;
  }
  if (i < 16384) {
    int f = i >> 7, k = i & 127;
    Wt1[k * 128 + f] = W1[i];
  } else if (i < 32768) {
    int j = i - 16384; int f = j >> 7, k = j & 127;
    Wt2[k * 128 + f] = W2[j];
  } else if (i < 81920) {
    int j = i - 32768; int f = j / 384, k = j % 384;
    Wc1t[k * 128 + f] = Wc1[j];
  } else if (i < 90112) {
    int j = i - 81920; int f = j >> 7, k = j & 127;
    Wc2t[k * 64 + f] = Wc2[j];
  }
}

// per-2048-chunk exclusive scan of PADDED counts (ceil(cnt/8)*8); bsum[b] = chunk total
__global__ void scan1_kernel(const int* __restrict__ cnt, int* __restrict__ prow,
                             int* __restrict__ bsum, int n) {
  __shared__ int smem[256];
  const int t = threadIdx.x;
  const int base = blockIdx.x * 2048 + t * 8;
  int v[8];
  int s = 0;
#pragma unroll
  for (int j = 0; j < 8; ++j) {
    int idx = base + j;
    v[j] = (idx < n) ? ((cnt[idx] + 7) & ~7) : 0;
    s += v[j];
  }
  smem[t] = s;
  __syncthreads();
  for (int off = 1; off < 256; off <<= 1) {
    int add = (t >= off) ? smem[t - off] : 0;
    __syncthreads();
    smem[t] += add;
    __syncthreads();
  }
  int run = smem[t] - s;
  if (t == 255) bsum[blockIdx.x] = smem[255];
#pragma unroll
  for (int j = 0; j < 8; ++j) {
    int idx = base + j;
    if (idx < n) prow[idx] = run;
    run += v[j];
  }
}

// 64-lane shuffle scan (nchunk=49 fits); appends grand total at bsum[nb]
__global__ void scan2_kernel(int* __restrict__ bsum, int nb) {
  const int t = threadIdx.x;
  if (nb <= 64) {
    const int orig = (t < nb) ? bsum[t] : 0;
    int v = orig;
#pragma unroll
    for (int off = 1; off < 64; off <<= 1) {
      int u = __shfl_up(v, off);
      if (t >= off) v += u;
    }
    if (t == nb - 1) bsum[nb] = v;
    if (t < nb) bsum[t] = v - orig;
  } else if (t == 0) {
    int run = 0;
    for (int i = 0; i < nb; ++i) { int v = bsum[i]; bsum[i] = run; run += v; }
    bsum[nb] = run;
  }
}

// atomic-free scatter into padded CSR, 4 edges/thread; threads i<n also zero
// their node's pad slots (real + pad slots exactly partition the padded CSR)
__global__ void scatter_kernel(const int* __restrict__ src, const int* __restrict__ dst,
                               const float* __restrict__ w, const int* __restrict__ prow,
                               const int* __restrict__ bsum, const int* __restrict__ rank,
                               const int* __restrict__ cnt,
                               int2* __restrict__ epack, int E, int n) {
  const int i = blockIdx.x * blockDim.x + threadIdx.x;
  int e = i * 4;
  if (e + 3 < E) {
    const int4 d = *(const int4*)&dst[e];
    const int4 s = *(const int4*)&src[e];
    const float4 wv = *(const float4*)&w[e];
    const int4 r = *(const int4*)&rank[e];
    epack[prow[d.x] + bsum[d.x >> 11] + r.x] = make_int2(s.x, __float_as_int(wv.x));
    epack[prow[d.y] + bsum[d.y >> 11] + r.y] = make_int2(s.y, __float_as_int(wv.y));
    epack[prow[d.z] + bsum[d.z >> 11] + r.z] = make_int2(s.z, __float_as_int(wv.z));
    epack[prow[d.w] + bsum[d.w >> 11] + r.w] = make_int2(s.w, __float_as_int(wv.w));
  } else {
    for (; e < E; ++e) {
      const int d = dst[e];
      epack[prow[d] + bsum[d >> 11] + rank[e]] = make_int2(src[e], __float_as_int(w[e]));
    }
  }
  if (i < n) {
    const int c = cnt[i];
    const int start = prow[i] + bsum[i >> 11] + c;
    const int pc = ((c + 7) & ~7) - c;
    for (int j = 0; j < pc; ++j) epack[start + j] = make_int2(0, 0);
  }
}

// Stage 1 (R14, proven): block's 32 rows = contiguous 8-aligned padded edge
// range, split into 8 laneset chunks. Per 8-edge batch: 8 independent 8B
// fp16-row gathers (from PREFETCHED descriptors; 2 cache lines per edge) +
// prefetch of next batch's 4 int4 descriptors + cvt + 32 FMA. Register acc
// flushes to LDS (permuted, bank=lane) only at row transitions. 8 blocks/CU.
// Stage 2: de-permute + (1+eps)x + agg/deg; self term from f32 xinf (conv1)
// or fp16 xinh (conv2, R20). Stage 3: GEMM (f32). Epilogue writes fp16 only.
__launch_bounds__(256, 8)
__global__ void conv_kernel(const float* __restrict__ xinf, const __half* __restrict__ xinh,
                            __half* __restrict__ xouth,
                            const int* __restrict__ prow, const int* __restrict__ bsum,
                            const int* __restrict__ cnt,
                            const int2* __restrict__ epack,
                            const float* __restrict__ Wt,
                            const float* __restrict__ bias, const float* __restrict__ eps,
                            int epsidx, int dorelu, int zerorow0, int selff32,
                            int n, int nchunk) {
  __shared__ float xm[CONV_NPB * 128];
  __shared__ int rp_s[CONV_NPB + 1];
  const int t = threadIdx.x;
  const int nb = blockIdx.x * CONV_NPB;
  const float epsv = 1.0f + eps[epsidx];

#pragma unroll
  for (int i = 0; i < 4; ++i)
    *(float4*)&xm[(t + i * 256) * 4] = make_float4(0.f, 0.f, 0.f, 0.f);
  if (t <= CONV_NPB) {
    const int node = nb + t;
    rp_s[t] = (node >= n) ? bsum[nchunk] : (prow[node] + bsum[node >> 11]);
  }
  __syncthreads();

  // ---- stage 1: padded 8-batch laneset fp16 gather with descriptor prefetch ----
  {
    const int L = t >> 5;
    const int lane = t & 31;
    const int f0 = lane * 4;
    const int e0 = rp_s[0], eT = rp_s[CONV_NPB];
    const int nbat = (eT - e0) >> 3;
    const int chunk = (((nbat + 7) >> 3)) << 3;
    const int jb = e0 + L * chunk;
    const int je = min(jb + chunk, eT);
    if (jb < je) {
      const int4* ep4 = (const int4*)epack;
      int r = 0;
      while (rp_s[r + 1] <= jb) ++r;
      float4 acc = make_float4(0.f, 0.f, 0.f, 0.f);
      // preload first batch's descriptors
      int h = jb >> 1;
      int4 q0 = ep4[h + 0];
      int4 q1 = ep4[h + 1];
      int4 q2 = ep4[h + 2];
      int4 q3 = ep4[h + 3];
      for (int j = jb; j < je; j += 8) {
        if (rp_s[r + 1] <= j) {
          float* bp = &xm[r * 128 + lane];
          atomicAdd(bp + 0,  acc.x);
          atomicAdd(bp + 32, acc.y);
          atomicAdd(bp + 64, acc.z);
          atomicAdd(bp + 96, acc.w);
          acc = make_float4(0.f, 0.f, 0.f, 0.f);
          do { ++r; } while (rp_s[r + 1] <= j);
        }
        // issue the 8 fp16 gathers for THIS batch (addresses already resident)
        const h4 u0 = *(const h4*)&xinh[(size_t)q0.x * 128 + f0];
        const h4 u1 = *(const h4*)&xinh[(size_t)q0.z * 128 + f0];
        const h4 u2 = *(const h4*)&xinh[(size_t)q1.x * 128 + f0];
        const h4 u3 = *(const h4*)&xinh[(size_t)q1.z * 128 + f0];
        const h4 u4 = *(const h4*)&xinh[(size_t)q2.x * 128 + f0];
        const h4 u5 = *(const h4*)&xinh[(size_t)q2.z * 128 + f0];
        const h4 u6 = *(const h4*)&xinh[(size_t)q3.x * 128 + f0];
        const h4 u7 = *(const h4*)&xinh[(size_t)q3.z * 128 + f0];
        const float w0 = __int_as_float(q0.y), w1 = __int_as_float(q0.w);
        const float w2 = __int_as_float(q1.y), w3 = __int_as_float(q1.w);
        const float w4 = __int_as_float(q2.y), w5 = __int_as_float(q2.w);
        const float w6 = __int_as_float(q3.y), w7 = __int_as_float(q3.w);
        // prefetch NEXT batch's descriptors (clamped, branch-free)
        const int jn = (j + 8 < je) ? (j + 8) : j;
        const int hn = jn >> 1;
        q0 = ep4[hn + 0];
        q1 = ep4[hn + 1];
        q2 = ep4[hn + 2];
        q3 = ep4[hn + 3];
        const float4 a0 = h4f(u0), a1 = h4f(u1), a2 = h4f(u2), a3 = h4f(u3);
        const float4 a4 = h4f(u4), a5 = h4f(u5), a6 = h4f(u6), a7 = h4f(u7);
        acc.x += w0 * a0.x + w1 * a1.x + w2 * a2.x + w3 * a3.x
               + w4 * a4.x + w5 * a5.x + w6 * a6.x + w7 * a7.x;
        acc.y += w0 * a0.y + w1 * a1.y + w2 * a2.y + w3 * a3.y
               + w4 * a4.y + w5 * a5.y + w6 * a6.y + w7 * a7.y;
        acc.z += w0 * a0.z + w1 * a1.z + w2 * a2.z + w3 * a3.z
               + w4 * a4.z + w5 * a5.z + w6 * a6.z + w7 * a7.z;
        acc.w += w0 * a0.w + w1 * a1.w + w2 * a2.w + w3 * a3.w
               + w4 * a4.w + w5 * a5.w + w6 * a6.w + w7 * a7.w;
      }
      float* bp = &xm[r * 128 + lane];
      atomicAdd(bp + 0,  acc.x);
      atomicAdd(bp + 32, acc.y);
      atomicAdd(bp + 64, acc.z);
      atomicAdd(bp + 96, acc.w);
    }
  }
  __syncthreads();

  // ---- stage 2: de-permute + finalize (1+eps)*x + agg/deg ----
  {
    float4 m[4];
#pragma unroll
    for (int q = 0; q < 4; ++q) {
      const int task = t + q * 256;
      const int r = task >> 5;
      const int fg = task & 31;
      m[q].x = xm[r * 128 + fg];
      m[q].y = xm[r * 128 + 32 + fg];
      m[q].z = xm[r * 128 + 64 + fg];
      m[q].w = xm[r * 128 + 96 + fg];
    }
    __syncthreads();
#pragma unroll
    for (int q = 0; q < 4; ++q) {
      const int task = t + q * 256;
      const int r = task >> 5;
      const int fg = task & 31;
      const int f0 = fg * 4;
      const int node = nb + r;
      float4 v = make_float4(0.f, 0.f, 0.f, 0.f);
      if (node < n) {
        const int d = cnt[node];
        const float rdeg = 1.0f / (float)(d > 1 ? d : 1);
        float4 xv;
        if (selff32) xv = *(const float4*)&xinf[(size_t)node * 128 + f0];
        else         xv = h4f(*(const h4*)&xinh[(size_t)node * 128 + f0]);
        v.x = epsv * xv.x + m[q].x * rdeg;
        v.y = epsv * xv.y + m[q].y * rdeg;
        v.z = epsv * xv.z + m[q].z * rdeg;
        v.w = epsv * xv.w + m[q].w * rdeg;
      }
      *(float4*)&xm[r * 128 + f0] = v;
    }
  }
  __syncthreads();

  // ---- stage 3: GEMM, thread tile = 4 rows x 4 features ----
  {
    const int fg = t & 31;
    const int rg = t >> 5;
    const int f0 = fg * 4;
    const int r0 = rg * 4;
    float4 acc[4];
#pragma unroll
    for (int r = 0; r < 4; ++r) acc[r] = make_float4(0.f, 0.f, 0.f, 0.f);
    for (int k = 0; k < 128; k += 4) {
      const float4 w0 = *(const float4*)&Wt[(k + 0) * 128 + f0];
      const float4 w1 = *(const float4*)&Wt[(k + 1) * 128 + f0];
      const float4 w2 = *(const float4*)&Wt[(k + 2) * 128 + f0];
      const float4 w3 = *(const float4*)&Wt[(k + 3) * 128 + f0];
#pragma unroll
      for (int r = 0; r < 4; ++r) {
        const float4 xv = *(const float4*)&xm[(r0 + r) * 128 + k];
        acc[r].x += xv.x * w0.x + xv.y * w1.x + xv.z * w2.x + xv.w * w3.x;
        acc[r].y += xv.x * w0.y + xv.y * w1.y + xv.z * w2.y + xv.w * w3.y;
        acc[r].z += xv.x * w0.z + xv.y * w1.z + xv.z * w2.z + xv.w * w3.z;
        acc[r].w += xv.x * w0.w + xv.y * w1.w + xv.z * w2.w + xv.w * w3.w;
      }
    }
    const float4 bv = *(const float4*)&bias[f0];
#pragma unroll
    for (int r = 0; r < 4; ++r) {
      const int node = nb + r0 + r;
      if (node < n) {
        float4 v;
        v.x = acc[r].x + bv.x;
        v.y = acc[r].y + bv.y;
        v.z = acc[r].z + bv.z;
        v.w = acc[r].w + bv.w;
        if (dorelu) {
          v.x = fmaxf(v.x, 0.f); v.y = fmaxf(v.y, 0.f);
          v.z = fmaxf(v.z, 0.f); v.w = fmaxf(v.w, 0.f);
        }
        if (zerorow0 && node == 0) { v.x = 0.f; v.y = 0.f; v.z = 0.f; v.w = 0.f; }
        *(h4*)&xouth[(size_t)node * 128 + f0] = f4h(v);
      }
    }
  }
}

// Final MLP: 8 elems per 256-thread block (512 blocks); x2 gathers in fp16.
__launch_bounds__(256, 4)
__global__ void final_kernel(const __half* __restrict__ x2h, const int* __restrict__ indices,
                             const float* __restrict__ Wc1t, const float* __restrict__ bc1,
                             const float* __restrict__ Wc2t, const float* __restrict__ bc2,
                             const float* __restrict__ Wc3, const float* __restrict__ bc3,
                             float* __restrict__ out) {
  __shared__ float ysm[FIN_EPB * 384];
  __shared__ float h1s[FIN_EPB * 128];
  __shared__ float h2s[FIN_EPB * 64];
  __shared__ int ind_s[FIN_EPB * 23];
  __shared__ float ccs[FIN_EPB];
  const int t = threadIdx.x;
  const int b0 = blockIdx.x * FIN_EPB;

  if (t < FIN_EPB * 23) ind_s[t] = indices[(size_t)b0 * 23 + t];
  __syncthreads();
  if (t < FIN_EPB) {
    int cc = 0;
#pragma unroll
    for (int j = 0; j < 20; ++j) cc += (ind_s[t * 23 + 3 + j] > 0) ? 1 : 0;
    ccs[t] = 1.0f / (float)(cc > 0 ? cc : 1);
  }
  __syncthreads();

  // ---- phase A ----
  {
#pragma unroll
    for (int q = 0; q < 2; ++q) {
      const int s = t + q * 256;
      const int e = s >> 6;
      const int hf = (s >> 5) & 1;
      const int fg = s & 31;
      const int idx = ind_s[e * 23 + hf];
      const h4 u = *(const h4*)&x2h[(size_t)idx * 128 + fg * 4];
      *(float4*)&ysm[e * 384 + hf * 128 + fg * 4] = h4f(u);
    }
    const int e = t >> 5;
    const int fg = t & 31;
    float4 acc = make_float4(0.f, 0.f, 0.f, 0.f);
#pragma unroll
    for (int j = 0; j < 20; ++j) {
      const int cj = ind_s[e * 23 + 3 + j];
      const h4 u = *(const h4*)&x2h[(size_t)cj * 128 + fg * 4];
      const float4 a = h4f(u);
      acc.x += a.x; acc.y += a.y; acc.z += a.z; acc.w += a.w;
    }
    const float sc = ccs[e];
    acc.x *= sc; acc.y *= sc; acc.z *= sc; acc.w *= sc;
    *(float4*)&ysm[e * 384 + 256 + fg * 4] = acc;
  }
  __syncthreads();

  // ---- phase B: layer 1 (384 -> 128), 4 elems per thread ----
  {
    const int f1 = t & 127;
    const int eh = t >> 7;
    float acc[4];
    const float b = bc1[f1];
#pragma unroll
    for (int i = 0; i < 4; ++i) acc[i] = b;
    for (int k = 0; k < 384; k += 4) {
      const float wv0 = Wc1t[(k + 0) * 128 + f1];
      const float wv1 = Wc1t[(k + 1) * 128 + f1];
      const float wv2 = Wc1t[(k + 2) * 128 + f1];
      const float wv3 = Wc1t[(k + 3) * 128 + f1];
#pragma unroll
      for (int i = 0; i < 4; ++i) {
        const float4 yv = *(const float4*)&ysm[(eh * 4 + i) * 384 + k];
        acc[i] += yv.x * wv0 + yv.y * wv1 + yv.z * wv2 + yv.w * wv3;
      }
    }
#pragma unroll
    for (int i = 0; i < 4; ++i)
      h1s[(eh * 4 + i) * 128 + f1] = fmaxf(acc[i], 0.f);
  }
  __syncthreads();

  // ---- phase C: layer 2 (128 -> 64), 2 elems per thread ----
  {
    const int f2 = t & 63;
    const int eg = t >> 6;
    float acc[2];
    const float b = bc2[f2];
#pragma unroll
    for (int i = 0; i < 2; ++i) acc[i] = b;
    for (int k = 0; k < 128; k += 4) {
      const float wv0 = Wc2t[(k + 0) * 64 + f2];
      const float wv1 = Wc2t[(k + 1) * 64 + f2];
      const float wv2 = Wc2t[(k + 2) * 64 + f2];
      const float wv3 = Wc2t[(k + 3) * 64 + f2];
#pragma unroll
      for (int i = 0; i < 2; ++i) {
        const float4 hv = *(const float4*)&h1s[(eg * 2 + i) * 128 + k];
        acc[i] += hv.x * wv0 + hv.y * wv1 + hv.z * wv2 + hv.w * wv3;
      }
    }
#pragma unroll
    for (int i = 0; i < 2; ++i)
      h2s[(eg * 2 + i) * 64 + f2] = fmaxf(acc[i], 0.f);
  }
  __syncthreads();

  // ---- phase D: layer 3 (64 -> 1), 32 lanes per element ----
  {
    const int e = t >> 5;
    const int l = t & 31;
    float p = h2s[e * 64 + l] * Wc3[l] + h2s[e * 64 + l + 32] * Wc3[l + 32];
#pragma unroll
    for (int o = 16; o > 0; o >>= 1) p += __shfl_down(p, o, 32);
    if (l == 0) out[b0 + e] = p + bc3[0];
  }
}

extern "C" void kernel_launch(void* const* d_in, const int* in_sizes, int n_in,
                              void* d_out, int out_size, void* d_ws, size_t ws_size,
                              hipStream_t stream) {
  const int* indices = (const int*)d_in[0];
  const int* src = (const int*)d_in[1];
  const int* dst = (const int*)d_in[2];
  const float* w = (const float*)d_in[3];
  const float* ndata = (const float*)d_in[4];
  const float* W1 = (const float*)d_in[5];
  const float* b1 = (const float*)d_in[6];
  const float* W2 = (const float*)d_in[7];
  const float* b2 = (const float*)d_in[8];
  const float* eps = (const float*)d_in[9];
  const float* Wc1 = (const float*)d_in[10];
  const float* bc1 = (const float*)d_in[11];
  const float* Wc2 = (const float*)d_in[12];
  const float* bc2 = (const float*)d_in[13];
  const float* Wc3 = (const float*)d_in[14];
  const float* bc3 = (const float*)d_in[15];
  float* out = (float*)d_out;

  const int E = in_sizes[1];
  const int N = in_sizes[4] / 128;
  const int B = in_sizes[0] / 23;

  char* ws = (char*)d_ws;
  size_t off = 0;
  auto alloc = [&](size_t bytes) -> char* {
    char* p = ws + off;
    off = (off + bytes + 255) & ~(size_t)255;
    return p;
  };
  const size_t Epad = (size_t)E + 8 * (size_t)N;   // worst-case padded edge count
  int* cnt = (int*)alloc((size_t)N * 4);
  int* prow = (int*)alloc((size_t)(N + 1) * 4);
  int* rank = (int*)alloc((size_t)E * 4);
  int* bsum = (int*)alloc(256 * 4);
  int2* epack = (int2*)alloc(Epad * 8);
  __half* xh0 = (__half*)alloc((size_t)N * 128 * 2);       // fp16 ndata; reused as x2h
  __half* x1h = (__half*)alloc((size_t)N * 128 * 2);       // fp16 x1
  float* Wt1 = (float*)alloc(16384 * 4);
  float* Wt2 = (float*)alloc(16384 * 4);
  float* Wc1t = (float*)alloc(49152 * 4);
  float* Wc2t = (float*)alloc(8192 * 4);
  __half* x2h = xh0;   // xh0 dead after conv1; conv2 writes x2 (fp16) here

  // cnt = 0 (stream-ordered; completes before inithist's atomics)
  (void)hipMemsetAsync(cnt, 0, (size_t)N * 4, stream);

  const int ncast = (N * 128 + 7) / 8;                     // 1.6M cast threads
  const int Eq = (E + 3) / 4;
  int ninit = (N > 90112) ? N : 90112;
  if (ncast > ninit) ninit = ncast;
  if (Eq > ninit) ninit = Eq;
  inithist_kernel<<<(ninit + 255) / 256, 256, 0, stream>>>(
      W1, W2, Wc1, Wc2, ndata, xh0, Wt1, Wt2, Wc1t, Wc2t, dst, cnt, rank, N, E);

  const int nchunk = (N + 2047) / 2048;
  scan1_kernel<<<nchunk, 256, 0, stream>>>(cnt, prow, bsum, N);
  scan2_kernel<<<1, 64, 0, stream>>>(bsum, nchunk);
  const int nsc = (Eq > N) ? Eq : N;
  scatter_kernel<<<(nsc + 255) / 256, 256, 0, stream>>>(src, dst, w, prow, bsum, rank, cnt, epack, E, N);

  const int nconv = (N + CONV_NPB - 1) / CONV_NPB;
  // conv1: gathers fp16(ndata); self term f32 ndata; writes x1h (fp16 only)
  conv_kernel<<<nconv, 256, 0, stream>>>(ndata, xh0, x1h, prow, bsum, cnt, epack,
                                         Wt1, b1, eps, 0, 1, 0, 1, N, nchunk);
  // conv2: gathers x1h; self term fp16 x1h; writes x2h (into xh0 buffer)
  conv_kernel<<<nconv, 256, 0, stream>>>(nullptr, x1h, x2h, prow, bsum, cnt, epack,
                                         Wt2, b2, eps, 1, 0, 1, 0, N, nchunk);

  final_kernel<<<B / FIN_EPB, 256, 0, stream>>>(x2h, indices, Wc1t, bc1, Wc2t, bc2, Wc3, bc3, out);
}